// Round 1
// baseline (13449.315 us; speedup 1.0000x reference)
//
#include <hip/hip_runtime.h>
#include <hip/hip_bf16.h>

// ELMo: 2-layer bidirectional masked LSTM + LN. B=32, T=256 (255 steps), E=512, U=1024.
// Strategy: fused x@W+h@U per-step MFMA in a persistent-ish scan kernel (128 WGs,
// per-direction atomic barrier each step, agent-scope fences for cross-XCD visibility).

#define B_  32
#define T_  256
#define TS  255
#define E_  512
#define U_  1024
#define G4  4096
#define ROWS 8160   // TS*B_

typedef __attribute__((ext_vector_type(8))) short short8;
typedef __attribute__((ext_vector_type(4))) float f32x4;

static __device__ __forceinline__ unsigned short f2bf(float f) {
    union { float f; unsigned int u; } x; x.f = f;
    unsigned int u = x.u;
    unsigned int r = (u + 0x7FFFu + ((u >> 16) & 1u)) >> 16;   // RNE
    return (unsigned short)r;
}
static __device__ __forceinline__ float bf2f(unsigned short u) {
    union { unsigned int u; float f; } x; x.u = ((unsigned int)u) << 16;
    return x.f;
}
static __device__ __forceinline__ float sigm(float x) { return 1.f / (1.f + __expf(-x)); }
static __device__ __forceinline__ float tanh_(float x) { return 2.f / (1.f + __expf(-2.f * x)) - 1.f; }

// ---------------- embedding gather -> bf16 [32][256][512] ----------------
__global__ __launch_bounds__(256) void gather_kernel(const int* __restrict__ x,
                                                     const float* __restrict__ emb,
                                                     unsigned short* __restrict__ ebf) {
    const int bt = blockIdx.x;                 // b*256 + t
    const int tok = x[bt];
    const float* src = emb + (size_t)tok * E_;
    const int c = threadIdx.x * 2;
    float2 v = *(const float2*)(src + c);
    unsigned int pk = (unsigned int)f2bf(v.x) | ((unsigned int)f2bf(v.y) << 16);
    *(unsigned int*)(ebf + (size_t)bt * E_ + c) = pk;
}

// ---------------- weight pack: [W;U] -> B-fragment-major bf16 ----------------
// frag (tau, kk, lane): 8 bf16, element j = Wc[kk*32 + (lane>>4)*8 + j][g*1024 + wcol*16 + (lane&15)]
// tau = wcol*4 + g, stored at dst[((tau*KK + kk)*64 + lane)*8]
__global__ __launch_bounds__(256) void pack_kernel(const float* __restrict__ W,
                                                   const float* __restrict__ Uw,
                                                   unsigned short* __restrict__ dst,
                                                   int Kin, int KK) {
    const int w = blockIdx.x * 4 + (threadIdx.x >> 6);
    const int lane = threadIdx.x & 63;
    const int tau = w / KK;
    const int kk = w - tau * KK;
    const int wcol = tau >> 2, g = tau & 3;
    const int col = g * 1024 + wcol * 16 + (lane & 15);
    const int kr0 = kk * 32 + ((lane >> 4) << 3);
    unsigned int pk[4];
#pragma unroll
    for (int jj = 0; jj < 4; ++jj) {
        float v0, v1;
        int kr = kr0 + jj * 2;
        v0 = (kr < Kin) ? W[(size_t)kr * G4 + col] : Uw[(size_t)(kr - Kin) * G4 + col];
        kr += 1;
        v1 = (kr < Kin) ? W[(size_t)kr * G4 + col] : Uw[(size_t)(kr - Kin) * G4 + col];
        pk[jj] = (unsigned int)f2bf(v0) | ((unsigned int)f2bf(v1) << 16);
    }
    uint4 o; o.x = pk[0]; o.y = pk[1]; o.z = pk[2]; o.w = pk[3];
    *(uint4*)(dst + ((size_t)(tau * KK + kk) * 64 + lane) * 8) = o;
}

// ---------------- persistent scan: one layer, both directions ----------------
template <int LAYER>
__global__ __launch_bounds__(256) void scan_kernel(
    const unsigned short* __restrict__ packF, const unsigned short* __restrict__ packB,
    const unsigned short* __restrict__ xsrc,   // L0: ebf [32][256][512]; L1: x1 [2][8160][1024]
    const int* __restrict__ xtok,              // [32][256]
    const float* __restrict__ biasF, const float* __restrict__ biasB,
    unsigned short* __restrict__ hcomm,        // [2 phase][2 dir][32][1024] bf16
    float* __restrict__ hstate,                // [2][32][1024]
    float* __restrict__ cstate,                // [2][32][1024]
    unsigned short* __restrict__ out0,         // [2][8160][1024] bf16 (pre-LN outputs)
    unsigned int* __restrict__ ctrs)           // [2] per-direction barrier counters
{
    constexpr int Kin = (LAYER == 0) ? E_ : U_;
    constexpr int KK  = (Kin + U_) / 32;       // 48 / 64
    constexpr int KKx = Kin / 32;              // 16 / 32
    constexpr int PH  = (LAYER == 0) ? 0 : 1;  // h_comm phase offset (255 steps is odd)

    const int wg = blockIdx.x;                 // 0..127
    const int dir = wg >> 6;
    const int wcol = wg & 63;
    const int tid = threadIdx.x;
    const int g = tid >> 6;                    // wave index == gate index
    const int lane = tid & 63;

    const unsigned short* pack = dir ? packB : packF;
    const float* bias = dir ? biasB : biasF;
    const short8* bbase = (const short8*)pack + (size_t)(wcol * 4 + g) * KK * 64 + lane;

    __shared__ float zbuf[32][65];

    // element-wise mapping: thread owns (b0,uu) and (b0+16,uu)
    const int uu = tid & 15;
    const int b0 = tid >> 4;                   // 0..15
    const int b1 = b0 + 16;
    const int ucol = (wcol << 4) + uu;
    const int sidx0 = (dir * 32 + b0) * U_ + ucol;
    const int sidx1 = (dir * 32 + b1) * U_ + ucol;

    float h0r = hstate[sidx0], h1r = hstate[sidx1];
    float c0r = cstate[sidx0], c1r = cstate[sidx1];
    float o0r = 0.f, o1r = 0.f;
    const float bi_ = bias[ucol], bf_ = bias[1024 + ucol];
    const float bg_ = bias[2048 + ucol], bo_ = bias[3072 + ucol];

    unsigned int* ctr = ctrs + dir;

    // MFMA A-fragment addressing (per lane)
    const int arow = lane & 15;
    const int kgrp = (lane >> 4) << 3;

    for (int s = 0; s < TS; ++s) {
        const int tcol = dir ? (TS - s) : s;
        f32x4 acc0 = {0.f, 0.f, 0.f, 0.f};
        f32x4 acc1 = {0.f, 0.f, 0.f, 0.f};
        const short8* bp = bbase;

        // phase 1: x part (K = Kin)
        {
            const unsigned short *a0, *a1;
            if (LAYER == 0) {
                a0 = xsrc + ((size_t)(arow)      * T_ + tcol) * E_ + kgrp;
                a1 = xsrc + ((size_t)(arow + 16) * T_ + tcol) * E_ + kgrp;
            } else {
                const size_t rb = (size_t)dir * ROWS + (size_t)s * 32;
                a0 = xsrc + (rb + arow)      * U_ + kgrp;
                a1 = xsrc + (rb + arow + 16) * U_ + kgrp;
            }
#pragma unroll 4
            for (int kk = 0; kk < KKx; ++kk) {
                short8 bw = *bp; bp += 64;
                short8 af0 = *(const short8*)a0; a0 += 32;
                short8 af1 = *(const short8*)a1; a1 += 32;
                acc0 = __builtin_amdgcn_mfma_f32_16x16x32_bf16(af0, bw, acc0, 0, 0, 0);
                acc1 = __builtin_amdgcn_mfma_f32_16x16x32_bf16(af1, bw, acc1, 0, 0, 0);
            }
        }
        // phase 2: h part (K = 1024) from double-buffered h_comm
        {
            const unsigned short* hrd = hcomm + (size_t)((s + PH) & 1) * (2 * 32 * U_);
            const unsigned short* a0 = hrd + (size_t)(dir * 32 + arow)      * U_ + kgrp;
            const unsigned short* a1 = hrd + (size_t)(dir * 32 + arow + 16) * U_ + kgrp;
#pragma unroll 4
            for (int kk = KKx; kk < KK; ++kk) {
                short8 bw = *bp; bp += 64;
                short8 af0 = *(const short8*)a0; a0 += 32;
                short8 af1 = *(const short8*)a1; a1 += 32;
                acc0 = __builtin_amdgcn_mfma_f32_16x16x32_bf16(af0, bw, acc0, 0, 0, 0);
                acc1 = __builtin_amdgcn_mfma_f32_16x16x32_bf16(af1, bw, acc1, 0, 0, 0);
            }
        }
        // scatter gate tiles to LDS: D layout col=lane&15, row=(lane>>4)*4+reg
        {
            const int zr = (lane >> 4) << 2;
            const int zc = (g << 4) | (lane & 15);
#pragma unroll
            for (int r2 = 0; r2 < 4; ++r2) {
                zbuf[zr + r2][zc]      = acc0[r2];
                zbuf[zr + r2 + 16][zc] = acc1[r2];
            }
        }
        __syncthreads();
        // element-wise LSTM cell + mask semantics
        {
            unsigned short* hwr = hcomm + (size_t)((s + PH + 1) & 1) * (2 * 32 * U_);
            const int m0 = xtok[b0 * T_ + tcol] != 0;
            const int m1 = xtok[b1 * T_ + tcol] != 0;

            float iv = zbuf[b0][uu] + bi_,      fv = zbuf[b0][16 + uu] + bf_;
            float gv = zbuf[b0][32 + uu] + bg_, ov = zbuf[b0][48 + uu] + bo_;
            float cn = sigm(fv) * c0r + sigm(iv) * tanh_(gv);
            float hn = sigm(ov) * tanh_(cn);
            if (m0) { c0r = cn; h0r = hn; o0r = hn; }

            iv = zbuf[b1][uu] + bi_;      fv = zbuf[b1][16 + uu] + bf_;
            gv = zbuf[b1][32 + uu] + bg_; ov = zbuf[b1][48 + uu] + bo_;
            cn = sigm(fv) * c1r + sigm(iv) * tanh_(gv);
            hn = sigm(ov) * tanh_(cn);
            if (m1) { c1r = cn; h1r = hn; o1r = hn; }

            hwr[sidx0] = f2bf(h0r);
            hwr[sidx1] = f2bf(h1r);
            out0[((size_t)dir * ROWS + (size_t)s * 32 + b0) * U_ + ucol] = f2bf(o0r);
            out0[((size_t)dir * ROWS + (size_t)s * 32 + b1) * U_ + ucol] = f2bf(o1r);
        }
        __syncthreads();
        // per-direction barrier (64 WGs), agent scope
        if (tid == 0) {
            __threadfence();
            __hip_atomic_fetch_add(ctr, 1u, __ATOMIC_RELEASE, __HIP_MEMORY_SCOPE_AGENT);
            const unsigned int tgt = (unsigned int)(s + 1) * 64u;
            while (__hip_atomic_load(ctr, __ATOMIC_ACQUIRE, __HIP_MEMORY_SCOPE_AGENT) < tgt)
                __builtin_amdgcn_s_sleep(2);
            __threadfence();
        }
        __syncthreads();
    }
    // publish final states for layer handoff
    hstate[sidx0] = h0r; hstate[sidx1] = h1r;
    cstate[sidx0] = c0r; cstate[sidx1] = c1r;
}

// ---------------- layernorm (per row of 1024) ----------------
__global__ __launch_bounds__(256) void ln_kernel(const unsigned short* __restrict__ in,
                                                 const float* __restrict__ gamma,
                                                 const float* __restrict__ beta,
                                                 unsigned short* __restrict__ outbf,
                                                 float* __restrict__ outf,
                                                 int final_) {
    const int r = blockIdx.x;          // 0..8159
    const int dir = blockIdx.y;        // 0..1
    const int s = r >> 5, b = r & 31;
    const size_t rowoff = ((size_t)dir * ROWS + r) * U_;
    const int tid = threadIdx.x;
    const int c = tid * 4;

    uint2 raw = *(const uint2*)(in + rowoff + c);
    float v0 = bf2f((unsigned short)(raw.x & 0xffff));
    float v1 = bf2f((unsigned short)(raw.x >> 16));
    float v2 = bf2f((unsigned short)(raw.y & 0xffff));
    float v3 = bf2f((unsigned short)(raw.y >> 16));

    float sum = v0 + v1 + v2 + v3;
    float sq = v0 * v0 + v1 * v1 + v2 * v2 + v3 * v3;
#pragma unroll
    for (int off = 32; off > 0; off >>= 1) {
        sum += __shfl_down(sum, off);
        sq  += __shfl_down(sq, off);
    }
    __shared__ float red[8];
    __shared__ float stats[2];
    const int wv = tid >> 6;
    if ((tid & 63) == 0) { red[wv] = sum; red[4 + wv] = sq; }
    __syncthreads();
    if (tid == 0) {
        float S = red[0] + red[1] + red[2] + red[3];
        float Q = red[4] + red[5] + red[6] + red[7];
        float mu = S * (1.f / 1024.f);
        float var = Q * (1.f / 1024.f) - mu * mu;
        stats[0] = mu;
        stats[1] = rsqrtf(var + 1e-3f);
    }
    __syncthreads();
    const float mu = stats[0], inv = stats[1];
    float y0 = (v0 - mu) * inv * gamma[c]     + beta[c];
    float y1 = (v1 - mu) * inv * gamma[c + 1] + beta[c + 1];
    float y2 = (v2 - mu) * inv * gamma[c + 2] + beta[c + 2];
    float y3 = (v3 - mu) * inv * gamma[c + 3] + beta[c + 3];

    if (!final_) {
        uint2 o;
        o.x = (unsigned int)f2bf(y0) | ((unsigned int)f2bf(y1) << 16);
        o.y = (unsigned int)f2bf(y2) | ((unsigned int)f2bf(y3) << 16);
        *(uint2*)(outbf + rowoff + c) = o;
    } else {
        const size_t tIdx = dir ? (size_t)(254 - s) : (size_t)s;   // backward dir un-reverses time
        const size_t o = (size_t)dir * ROWS * U_ + ((size_t)b * TS + tIdx) * U_ + c;
        float4 y; y.x = y0; y.y = y1; y.z = y2; y.w = y3;
        *(float4*)(outf + o) = y;
    }
}

// ---------------- host ----------------
extern "C" void kernel_launch(void* const* d_in, const int* in_sizes, int n_in,
                              void* d_out, int out_size, void* d_ws, size_t ws_size,
                              hipStream_t stream) {
    (void)in_sizes; (void)n_in; (void)out_size; (void)ws_size;
    const int*   x   = (const int*)d_in[0];
    const float* emb = (const float*)d_in[1];
    const float* fW0 = (const float*)d_in[2];
    const float* fU0 = (const float*)d_in[3];
    const float* fb0 = (const float*)d_in[4];
    const float* bW0 = (const float*)d_in[5];
    const float* bU0 = (const float*)d_in[6];
    const float* bb0 = (const float*)d_in[7];
    const float* g0  = (const float*)d_in[8];
    const float* be0 = (const float*)d_in[9];
    const float* fW1 = (const float*)d_in[10];
    const float* fU1 = (const float*)d_in[11];
    const float* fb1 = (const float*)d_in[12];
    const float* bW1 = (const float*)d_in[13];
    const float* bU1 = (const float*)d_in[14];
    const float* bb1 = (const float*)d_in[15];
    const float* g1  = (const float*)d_in[16];
    const float* be1 = (const float*)d_in[17];

    char* ws = (char*)d_ws;
    size_t off = 0;
    auto alloc = [&](size_t bytes) -> void* {
        void* p = ws + off;
        off = (off + bytes + 255) & ~(size_t)255;
        return p;
    };
    const size_t SZ_P0  = (size_t)256 * 48 * 64 * 16;   // 12.58 MB
    const size_t SZ_P1  = (size_t)256 * 64 * 64 * 16;   // 16.78 MB
    const size_t SZ_EBF = (size_t)B_ * T_ * E_ * 2;     // 8.39 MB
    const size_t SZ_ACT = (size_t)2 * ROWS * U_ * 2;    // 33.42 MB

    unsigned short* P0f = (unsigned short*)alloc(SZ_P0);
    unsigned short* P0b = (unsigned short*)alloc(SZ_P0);
    unsigned short* P1f = (unsigned short*)alloc(SZ_P1);
    unsigned short* P1b = (unsigned short*)alloc(SZ_P1);
    unsigned short* ebf = (unsigned short*)alloc(SZ_EBF);
    unsigned short* x1  = (unsigned short*)alloc(SZ_ACT);
    unsigned short* out0= (unsigned short*)alloc(SZ_ACT);
    char* stateblob     = (char*)alloc(262144 * 3 + 256);

    unsigned short* hcomm = (unsigned short*)stateblob;            // 262144 B
    float* hstate = (float*)(stateblob + 262144);                  // 262144 B
    float* cstate = (float*)(stateblob + 524288);                  // 262144 B
    unsigned int* ctrs = (unsigned int*)(stateblob + 786432);      // 4 counters

    hipMemsetAsync(stateblob, 0, 262144 * 3 + 256, stream);

    gather_kernel<<<dim3(B_ * T_), 256, 0, stream>>>(x, emb, ebf);
    pack_kernel<<<dim3(256 * 48 / 4), 256, 0, stream>>>(fW0, fU0, P0f, E_, 48);
    pack_kernel<<<dim3(256 * 48 / 4), 256, 0, stream>>>(bW0, bU0, P0b, E_, 48);
    pack_kernel<<<dim3(256 * 64 / 4), 256, 0, stream>>>(fW1, fU1, P1f, U_, 64);
    pack_kernel<<<dim3(256 * 64 / 4), 256, 0, stream>>>(bW1, bU1, P1b, U_, 64);

    scan_kernel<0><<<dim3(128), 256, 0, stream>>>(P0f, P0b, ebf, x, fb0, bb0,
                                                  hcomm, hstate, cstate, out0, ctrs);
    ln_kernel<<<dim3(ROWS, 2), 256, 0, stream>>>(out0, g0, be0, x1, nullptr, 0);
    scan_kernel<1><<<dim3(128), 256, 0, stream>>>(P1f, P1b, x1, x, fb1, bb1,
                                                  hcomm, hstate, cstate, out0, ctrs + 2);
    ln_kernel<<<dim3(ROWS, 2), 256, 0, stream>>>(out0, g1, be1, nullptr, (float*)d_out, 1);
}

// Round 3
// 7640.887 us; speedup vs baseline: 1.7602x; 1.7602x over previous
//
#include <hip/hip_runtime.h>
#include <hip/hip_bf16.h>

// ELMo: 2-layer bidirectional masked LSTM + LN. B=32, T=256 (255 steps), E=512, U=1024.
// R3: same persistent-RNN design as R2, workspace aliased down to ~219 MB
// (R2's ~270 MB likely overran ws_size -> HSA memory fault / abort).

#define B_  32
#define T_  256
#define TS  255
#define E_  512
#define U_  1024
#define G4  4096
#define ROWS 8160        // TS*B_
#define SROWS 8192       // padded per-dir row stride for out0/x1/Xw

typedef __attribute__((ext_vector_type(8))) short short8;
typedef __attribute__((ext_vector_type(4))) float f32x4;
typedef __attribute__((ext_vector_type(16))) float f32x16;

static __device__ __forceinline__ unsigned short f2bf(float f) {
    union { float f; unsigned int u; } x; x.f = f;
    unsigned int u = x.u;
    unsigned int r = (u + 0x7FFFu + ((u >> 16) & 1u)) >> 16;   // RNE
    return (unsigned short)r;
}
static __device__ __forceinline__ float bf2f(unsigned short u) {
    union { unsigned int u; float f; } x; x.u = ((unsigned int)u) << 16;
    return x.f;
}
static __device__ __forceinline__ float sigm(float x) { return 1.f / (1.f + __expf(-x)); }
static __device__ __forceinline__ float tanh_(float x) { return 2.f / (1.f + __expf(-2.f * x)) - 1.f; }

static __device__ __forceinline__ void gload_lds16(const void* g, void* l) {
    __builtin_amdgcn_global_load_lds(
        (const __attribute__((address_space(1))) unsigned int*)g,
        (__attribute__((address_space(3))) unsigned int*)l, 16, 0, 0);
}

// ---------------- embedding gather -> bf16 [32][256][512] (row = b*256+t) ----------------
__global__ __launch_bounds__(256) void gather_kernel(const int* __restrict__ x,
                                                     const float* __restrict__ emb,
                                                     unsigned short* __restrict__ ebf) {
    const int bt = blockIdx.x;
    const int tok = x[bt];
    const float* src = emb + (size_t)tok * E_;
    const int c = threadIdx.x * 2;
    float2 v = *(const float2*)(src + c);
    unsigned int pk = (unsigned int)f2bf(v.x) | ((unsigned int)f2bf(v.y) << 16);
    *(unsigned int*)(ebf + (size_t)bt * E_ + c) = pk;
}

// ---------------- weight pack -> 32x32x16 B-fragment-major bf16 ----------------
// frag (tau32, kk16): lane l holds 8 bf16: col = colmap(tau32*32 + (l&31)),
//                     k = kk16*16 + (l>>5)*8 + j.  dst[(fid*64+l)*8], fid = tau32*KK16 + kk16.
// PERM=1 (scan U): vcol = wcol*64 + g*16 + uu -> actual col g*1024 + wcol*16 + uu.
__global__ __launch_bounds__(256) void pack_frag(const float* __restrict__ src,
                                                 unsigned short* __restrict__ dst,
                                                 int KK16, int PERM) {
    const int fid = blockIdx.x * 4 + (threadIdx.x >> 6);
    const int lane = threadIdx.x & 63;
    const int tau = fid / KK16;
    const int kk = fid - tau * KK16;
    int vcol = tau * 32 + (lane & 31);
    int col;
    if (PERM) {
        int wc = vcol >> 6, g = (vcol >> 4) & 3, uu = vcol & 15;
        col = g * 1024 + wc * 16 + uu;
    } else col = vcol;
    const int k0 = kk * 16 + ((lane >> 5) << 3);
    unsigned int pk[4];
#pragma unroll
    for (int jj = 0; jj < 4; ++jj) {
        float v0 = src[(size_t)(k0 + jj * 2) * G4 + col];
        float v1 = src[(size_t)(k0 + jj * 2 + 1) * G4 + col];
        pk[jj] = (unsigned int)f2bf(v0) | ((unsigned int)f2bf(v1) << 16);
    }
    uint4 o; o.x = pk[0]; o.y = pk[1]; o.z = pk[2]; o.w = pk[3];
    *(uint4*)(dst + ((size_t)fid * 64 + lane) * 8) = o;
}

// ---------------- Xw GEMM: C[dir][row][4096] = A[row][K] @ W + bias (bf16 out) ----------------
template <int KK16>
__global__ __launch_bounds__(256) void gemm_xw(
    const unsigned short* __restrict__ Abase, unsigned long long adstride,
    const unsigned short* __restrict__ P0, const unsigned short* __restrict__ P1,
    const float* __restrict__ bias0, const float* __restrict__ bias1,
    unsigned short* __restrict__ C)
{
    constexpr int K = KK16 * 16;
    constexpr int NT = KK16 / 4;                   // BK=64 tiles
    __shared__ unsigned short alds[2][128 * 64];   // 2 x 16KB
    const int bm = blockIdx.x, bn = blockIdx.y, dir = blockIdx.z;
    const unsigned short* A = Abase + (size_t)dir * adstride;
    const unsigned short* P = dir ? P1 : P0;
    const float* bias = dir ? bias1 : bias0;
    unsigned short* Cd = C + (size_t)dir * SROWS * G4;
    const int tid = threadIdx.x, w = tid >> 6, lane = tid & 63;
    const int l31 = lane & 31, lhi = lane >> 5;

    f32x16 acc0, acc1;
#pragma unroll
    for (int i = 0; i < 16; ++i) { acc0[i] = 0.f; acc1[i] = 0.f; }

    const int swz_in = (lane & 7) * 16;

#define STAGE(buf, kt)                                                                     \
    {                                                                                      \
        _Pragma("unroll")                                                                  \
        for (int i = 0; i < 4; ++i) {                                                      \
            const int idx = w * 4 + i;                                                     \
            const int row = idx * 8 + (lane >> 3);                                         \
            const int inrow = swz_in ^ ((row & 7) << 4);                                   \
            const unsigned short* src = A + (size_t)(bm * 128 + row) * K + (kt) * 64 + (inrow >> 1); \
            gload_lds16(src, (char*)&alds[buf][0] + idx * 1024);                           \
        }                                                                                  \
    }

    STAGE(0, 0);
    __syncthreads();
    for (int kt = 0; kt < NT; ++kt) {
        if (kt + 1 < NT) STAGE((kt + 1) & 1, kt + 1);
        const char* ab = (const char*)&alds[kt & 1][0];
        const int arow = w * 32 + l31;
#pragma unroll
        for (int kk = 0; kk < 4; ++kk) {
            const int koff = (kk * 32 + lhi * 16) ^ ((arow & 7) << 4);
            short8 af = *(const short8*)(ab + arow * 128 + koff);
            short8 bf0 = *(const short8*)(P + ((size_t)((bn * 2 + 0) * KK16 + kt * 4 + kk) * 64 + lane) * 8);
            short8 bf1 = *(const short8*)(P + ((size_t)((bn * 2 + 1) * KK16 + kt * 4 + kk) * 64 + lane) * 8);
            acc0 = __builtin_amdgcn_mfma_f32_32x32x16_bf16(af, bf0, acc0, 0, 0, 0);
            acc1 = __builtin_amdgcn_mfma_f32_32x32x16_bf16(af, bf1, acc1, 0, 0, 0);
        }
        __syncthreads();
    }
#undef STAGE
    const int col0 = bn * 64 + l31;
    const int col1 = col0 + 32;
    const float bv0 = bias[col0], bv1 = bias[col1];
#pragma unroll
    for (int reg = 0; reg < 16; ++reg) {
        const int r = (reg & 3) + 8 * (reg >> 2) + 4 * lhi;
        const size_t row = (size_t)bm * 128 + w * 32 + r;
        Cd[row * G4 + col0] = f2bf(acc0[reg] + bv0);
        Cd[row * G4 + col1] = f2bf(acc1[reg] + bv1);
    }
}

// ---------------- persistent scan: one layer, both dirs, U-weights in VGPRs ----------------
// 128 WGs: dir = wg>>6, wcol = wg&63 (16 ucols). 4 waves = K-quarters.
template <int LAYER>
__global__ __launch_bounds__(256, 1) void scan_kernel(
    const unsigned short* __restrict__ puF, const unsigned short* __restrict__ puB,
    const unsigned short* __restrict__ Xw,     // [2][SROWS][4096] bf16 (L0 row=b*256+t, L1 row=s*32+b)
    const int* __restrict__ xtok,
    unsigned short* __restrict__ hcomm,        // [2 phase][2 dir][32][1024] bf16
    float* __restrict__ hstate, float* __restrict__ cstate,
    unsigned short* __restrict__ out0,         // [2][SROWS][1024] bf16
    unsigned int* __restrict__ ctrs)
{
    constexpr int PH = (LAYER == 0) ? 0 : 1;
    __shared__ unsigned short h_lds[32][1024];     // 64KB, XOR-swizzled storage
    __shared__ float zbuf[4][32][72];              // 36.9KB

    const int wg = blockIdx.x, dir = wg >> 6, wcol = wg & 63;
    const int tid = threadIdx.x, kq = tid >> 6, lane = tid & 63;
    const int l31 = lane & 31, lhi = lane >> 5;
    const unsigned short* pu = dir ? puB : puF;

    // ---- weight preload: wf[ct][kk] ----
    short8 wf[2][16];
#pragma unroll
    for (int ct = 0; ct < 2; ++ct)
#pragma unroll
        for (int kk = 0; kk < 16; ++kk) {
            size_t fid = (size_t)(wcol * 2 + ct) * 64 + (kq * 16 + kk);
            wf[ct][kk] = *(const short8*)(pu + (fid * 64 + lane) * 8);
        }

    // ---- elementwise ids: thread owns cells (b, uu0) and (b, uu0+1) ----
    const int b = tid >> 3, up = tid & 7, uu0 = up * 2;
    const int ucolb = wcol * 16;
    const int sbase = (dir * 32 + b) * U_ + ucolb + uu0;     // into [2][32][1024]
    float c0 = cstate[sbase], c1 = cstate[sbase + 1];
    float h0 = hstate[sbase], h1 = hstate[sbase + 1];
    float o0 = 0.f, o1 = 0.f;
    unsigned int* ctr = ctrs + dir;
    const unsigned short* xwbase = Xw + (size_t)dir * SROWS * G4;

    for (int s = 0; s < TS; ++s) {
        const int tcol = dir ? (TS - s) : s;
        // -- stage h[phase] -> LDS (swizzled via pre-swizzled source) --
        const unsigned short* hrd = hcomm + (size_t)((s + PH) & 1) * (2 * 32 * U_) + dir * 32 * U_;
#pragma unroll
        for (int i = 0; i < 16; ++i) {
            const int idx = kq * 16 + i;
            const int row = idx >> 1;
            const int inrow = ((idx & 1) * 1024 + lane * 16) ^ ((row & 7) << 4);
            gload_lds16((const char*)hrd + row * 2048 + inrow,
                        (char*)&h_lds[0][0] + idx * 1024);
        }
        // -- Xw + mask prefetch (held in regs across barriers) --
        const size_t xr = (LAYER == 0) ? ((size_t)b * T_ + tcol) : ((size_t)s * 32 + b);
        const unsigned short* xp = xwbase + xr * G4 + ucolb + uu0;
        const unsigned int xwi = *(const unsigned int*)(xp);
        const unsigned int xwf = *(const unsigned int*)(xp + 1024);
        const unsigned int xwg = *(const unsigned int*)(xp + 2048);
        const unsigned int xwo = *(const unsigned int*)(xp + 3072);
        const int m = xtok[b * T_ + tcol] != 0;
        __syncthreads();                           // h_lds ready (vmcnt drained)

        // -- MFMA: h @ U (K-quarter kq) --
        f32x16 a0, a1;
#pragma unroll
        for (int i = 0; i < 16; ++i) { a0[i] = 0.f; a1[i] = 0.f; }
        const char* hb = (const char*)&h_lds[0][0] + l31 * 2048;
        const int swz = (l31 & 7) << 4;
#pragma unroll
        for (int kk = 0; kk < 16; ++kk) {
            const int koff = ((kq * 16 + kk) * 32 + lhi * 16) ^ swz;
            short8 af = *(const short8*)(hb + koff);
            a0 = __builtin_amdgcn_mfma_f32_32x32x16_bf16(af, wf[0][kk], a0, 0, 0, 0);
            a1 = __builtin_amdgcn_mfma_f32_32x32x16_bf16(af, wf[1][kk], a1, 0, 0, 0);
        }
        // scatter to zbuf (D: col = l&31, row = (reg&3)+8*(reg>>2)+4*(l>>5))
#pragma unroll
        for (int reg = 0; reg < 16; ++reg) {
            const int zr = (reg & 3) + 8 * (reg >> 2) + 4 * lhi;
            zbuf[kq][zr][l31] = a0[reg];
            zbuf[kq][zr][32 + l31] = a1[reg];
        }
        __syncthreads();

        // -- elementwise cell (2 cells/thread) --
        {
            const int gi = uu0, gf = 16 + uu0, gg = 32 + uu0, go = 48 + uu0;
            float zi0 = zbuf[0][b][gi] + zbuf[1][b][gi] + zbuf[2][b][gi] + zbuf[3][b][gi] + bf2f((unsigned short)(xwi & 0xffff));
            float zf0 = zbuf[0][b][gf] + zbuf[1][b][gf] + zbuf[2][b][gf] + zbuf[3][b][gf] + bf2f((unsigned short)(xwf & 0xffff));
            float zg0 = zbuf[0][b][gg] + zbuf[1][b][gg] + zbuf[2][b][gg] + zbuf[3][b][gg] + bf2f((unsigned short)(xwg & 0xffff));
            float zo0 = zbuf[0][b][go] + zbuf[1][b][go] + zbuf[2][b][go] + zbuf[3][b][go] + bf2f((unsigned short)(xwo & 0xffff));
            float zi1 = zbuf[0][b][gi + 1] + zbuf[1][b][gi + 1] + zbuf[2][b][gi + 1] + zbuf[3][b][gi + 1] + bf2f((unsigned short)(xwi >> 16));
            float zf1 = zbuf[0][b][gf + 1] + zbuf[1][b][gf + 1] + zbuf[2][b][gf + 1] + zbuf[3][b][gf + 1] + bf2f((unsigned short)(xwf >> 16));
            float zg1 = zbuf[0][b][gg + 1] + zbuf[1][b][gg + 1] + zbuf[2][b][gg + 1] + zbuf[3][b][gg + 1] + bf2f((unsigned short)(xwg >> 16));
            float zo1 = zbuf[0][b][go + 1] + zbuf[1][b][go + 1] + zbuf[2][b][go + 1] + zbuf[3][b][go + 1] + bf2f((unsigned short)(xwo >> 16));

            float cn = sigm(zf0) * c0 + sigm(zi0) * tanh_(zg0);
            float hn = sigm(zo0) * tanh_(cn);
            if (m) { c0 = cn; h0 = hn; o0 = hn; }
            cn = sigm(zf1) * c1 + sigm(zi1) * tanh_(zg1);
            hn = sigm(zo1) * tanh_(cn);
            if (m) { c1 = cn; h1 = hn; o1 = hn; }

            unsigned short* hwr = hcomm + (size_t)((s + PH + 1) & 1) * (2 * 32 * U_);
            *(unsigned int*)(hwr + sbase) = (unsigned int)f2bf(h0) | ((unsigned int)f2bf(h1) << 16);
            const size_t orow = (size_t)dir * SROWS + (size_t)s * 32 + b;
            *(unsigned int*)(out0 + orow * U_ + ucolb + uu0) =
                (unsigned int)f2bf(o0) | ((unsigned int)f2bf(o1) << 16);
        }
        __syncthreads();
        // -- per-direction barrier (64 WGs), agent scope --
        if (tid == 0) {
            __threadfence();
            __hip_atomic_fetch_add(ctr, 1u, __ATOMIC_RELEASE, __HIP_MEMORY_SCOPE_AGENT);
            const unsigned int tgt = (unsigned int)(s + 1) * 64u;
            while (__hip_atomic_load(ctr, __ATOMIC_ACQUIRE, __HIP_MEMORY_SCOPE_AGENT) < tgt)
                __builtin_amdgcn_s_sleep(2);
            __threadfence();
        }
        __syncthreads();
    }
    hstate[sbase] = h0; hstate[sbase + 1] = h1;
    cstate[sbase] = c0; cstate[sbase + 1] = c1;
}

// ---------------- layernorm (per row of 1024) ----------------
__global__ __launch_bounds__(256) void ln_kernel(const unsigned short* __restrict__ in,
                                                 const float* __restrict__ gamma,
                                                 const float* __restrict__ beta,
                                                 unsigned short* __restrict__ outbf,
                                                 float* __restrict__ outf,
                                                 int final_) {
    const int r = blockIdx.x;          // 0..8159 (= s*32+b)
    const int dir = blockIdx.y;
    const int s = r >> 5, bb = r & 31;
    const size_t rowoff = ((size_t)dir * SROWS + r) * U_;
    const int tid = threadIdx.x;
    const int c = tid * 4;

    uint2 raw = *(const uint2*)(in + rowoff + c);
    float v0 = bf2f((unsigned short)(raw.x & 0xffff));
    float v1 = bf2f((unsigned short)(raw.x >> 16));
    float v2 = bf2f((unsigned short)(raw.y & 0xffff));
    float v3 = bf2f((unsigned short)(raw.y >> 16));

    float sum = v0 + v1 + v2 + v3;
    float sq = v0 * v0 + v1 * v1 + v2 * v2 + v3 * v3;
#pragma unroll
    for (int off = 32; off > 0; off >>= 1) {
        sum += __shfl_down(sum, off);
        sq  += __shfl_down(sq, off);
    }
    __shared__ float red[8];
    __shared__ float stats[2];
    const int wv = tid >> 6;
    if ((tid & 63) == 0) { red[wv] = sum; red[4 + wv] = sq; }
    __syncthreads();
    if (tid == 0) {
        float S = red[0] + red[1] + red[2] + red[3];
        float Q = red[4] + red[5] + red[6] + red[7];
        float mu = S * (1.f / 1024.f);
        float var = Q * (1.f / 1024.f) - mu * mu;
        stats[0] = mu;
        stats[1] = rsqrtf(var + 1e-3f);
    }
    __syncthreads();
    const float mu = stats[0], inv = stats[1];
    float y0 = (v0 - mu) * inv * gamma[c]     + beta[c];
    float y1 = (v1 - mu) * inv * gamma[c + 1] + beta[c + 1];
    float y2 = (v2 - mu) * inv * gamma[c + 2] + beta[c + 2];
    float y3 = (v3 - mu) * inv * gamma[c + 3] + beta[c + 3];

    if (!final_) {
        uint2 o;
        o.x = (unsigned int)f2bf(y0) | ((unsigned int)f2bf(y1) << 16);
        o.y = (unsigned int)f2bf(y2) | ((unsigned int)f2bf(y3) << 16);
        *(uint2*)(outbf + rowoff + c) = o;
    } else {
        const size_t tIdx = dir ? (size_t)(254 - s) : (size_t)s;
        const size_t o = (size_t)dir * ROWS * U_ + ((size_t)bb * TS + tIdx) * U_ + c;
        float4 y; y.x = y0; y.y = y1; y.z = y2; y.w = y3;
        *(float4*)(outf + o) = y;
    }
}

// ---------------- host ----------------
extern "C" void kernel_launch(void* const* d_in, const int* in_sizes, int n_in,
                              void* d_out, int out_size, void* d_ws, size_t ws_size,
                              hipStream_t stream) {
    (void)in_sizes; (void)n_in; (void)out_size; (void)ws_size;
    const int*   x   = (const int*)d_in[0];
    const float* emb = (const float*)d_in[1];
    const float* fW0 = (const float*)d_in[2];
    const float* fU0 = (const float*)d_in[3];
    const float* fb0 = (const float*)d_in[4];
    const float* bW0 = (const float*)d_in[5];
    const float* bU0 = (const float*)d_in[6];
    const float* bb0 = (const float*)d_in[7];
    const float* g0  = (const float*)d_in[8];
    const float* be0 = (const float*)d_in[9];
    const float* fW1 = (const float*)d_in[10];
    const float* fU1 = (const float*)d_in[11];
    const float* fb1 = (const float*)d_in[12];
    const float* bW1 = (const float*)d_in[13];
    const float* bU1 = (const float*)d_in[14];
    const float* bb1 = (const float*)d_in[15];
    const float* g1  = (const float*)d_in[16];
    const float* be1 = (const float*)d_in[17];

    // ---- aliased workspace layout (total ~218.9 MB) ----
    const size_t MB8  = 8388608;       // 8 MiB
    const size_t MB4  = 4194304;
    char* ws = (char*)d_ws;
    // S0: 32 MiB — ebf|pu0f|pu0b|pw0f|pw0b, all dead after scan<0>; reused as x1
    char* S0 = ws;
    unsigned short* ebf  = (unsigned short*)(S0);
    unsigned short* pu0f = (unsigned short*)(S0 + MB8);
    unsigned short* pu0b = (unsigned short*)(S0 + 2 * MB8);
    unsigned short* pw0f = (unsigned short*)(S0 + 3 * MB8);
    unsigned short* pw0b = (unsigned short*)(S0 + 3 * MB8 + MB4);
    unsigned short* x1   = (unsigned short*)(S0);            // alias (after scan<0>)
    // S1: 16 MiB — pw1f|pw1b (dead after gemm1) -> pu1f|pu1b
    char* S1 = ws + 4 * MB8;
    unsigned short* pw1f = (unsigned short*)(S1);
    unsigned short* pw1b = (unsigned short*)(S1 + MB8);
    unsigned short* pu1f = (unsigned short*)(S1);            // alias (after gemm1)
    unsigned short* pu1b = (unsigned short*)(S1 + MB8);
    // out0: 32 MiB
    unsigned short* out0 = (unsigned short*)(ws + 6 * MB8);
    // Xw: 128 MiB
    unsigned short* Xw   = (unsigned short*)(ws + 10 * MB8);
    // state: at 26*MB8 (= 218.1 MB)
    char* stateblob = ws + 26 * MB8;
    unsigned short* hcomm = (unsigned short*)stateblob;            // 262144 B
    float* hstate = (float*)(stateblob + 262144);
    float* cstate = (float*)(stateblob + 524288);
    unsigned int* ctrs = (unsigned int*)(stateblob + 786432);

    hipMemsetAsync(stateblob, 0, 262144 * 3 + 256, stream);

    gather_kernel<<<dim3(B_ * T_), 256, 0, stream>>>(x, emb, ebf);

    pack_frag<<<dim3(128 * 64 / 4), 256, 0, stream>>>(fU0, pu0f, 64, 1);
    pack_frag<<<dim3(128 * 64 / 4), 256, 0, stream>>>(bU0, pu0b, 64, 1);
    pack_frag<<<dim3(128 * 32 / 4), 256, 0, stream>>>(fW0, pw0f, 32, 0);
    pack_frag<<<dim3(128 * 32 / 4), 256, 0, stream>>>(bW0, pw0b, 32, 0);
    pack_frag<<<dim3(128 * 64 / 4), 256, 0, stream>>>(fW1, pw1f, 64, 0);
    pack_frag<<<dim3(128 * 64 / 4), 256, 0, stream>>>(bW1, pw1b, 64, 0);

    // Xw0 = e @ W0 + b0  (rows = b*256+t, 8192)
    gemm_xw<32><<<dim3(64, 64, 2), 256, 0, stream>>>(ebf, 0ull, pw0f, pw0b, fb0, bb0, Xw);
    scan_kernel<0><<<dim3(128), 256, 0, stream>>>(pu0f, pu0b, Xw, x, hcomm, hstate, cstate, out0, ctrs);
    // ln0: out0 -> x1 (x1 aliases S0; all S0 occupants dead by now)
    ln_kernel<<<dim3(ROWS, 2), 256, 0, stream>>>(out0, g0, be0, x1, nullptr, 0);
    // Xw1 = x1 @ W1 + b1  (rows = s*32+b, 8160 valid of 8192)
    gemm_xw<64><<<dim3(64, 64, 2), 256, 0, stream>>>(x1, (unsigned long long)SROWS * U_, pw1f, pw1b, fb1, bb1, Xw);
    // pack pu1 AFTER gemm1 (pu1 aliases pw1's storage)
    pack_frag<<<dim3(128 * 64 / 4), 256, 0, stream>>>(fU1, pu1f, 64, 1);
    pack_frag<<<dim3(128 * 64 / 4), 256, 0, stream>>>(bU1, pu1b, 64, 1);
    scan_kernel<1><<<dim3(128), 256, 0, stream>>>(pu1f, pu1b, Xw, x, hcomm, hstate, cstate, out0, ctrs + 2);
    ln_kernel<<<dim3(ROWS, 2), 256, 0, stream>>>(out0, g1, be1, nullptr, (float*)d_out, 1);
}

// Round 4
// 4156.236 us; speedup vs baseline: 3.2359x; 1.8384x over previous
//
#include <hip/hip_runtime.h>
#include <hip/hip_bf16.h>

// ELMo: 2-layer bidirectional masked LSTM + LN. B=32, T=256 (255 steps), E=512, U=1024.
// R4: persistent scan with cache-bypassing (sc0/sc1) cross-XCD communication:
//  - h exchange + flags via RELAXED agent-scope atomics (no buffer_wbl2/buffer_inv per step)
//  - per-WG flag words + coalesced 32-lane poll (no contended counter)
//  - 64 WGs x 512 threads, U-weights pinned in 128 VGPR/wave.

#define B_  32
#define T_  256
#define TS  255
#define E_  512
#define U_  1024
#define G4  4096
#define ROWS 8160        // TS*B_
#define SROWS 8192       // padded per-dir row stride for out0/x1/Xw

typedef __attribute__((ext_vector_type(8))) short short8;
typedef __attribute__((ext_vector_type(16))) float f32x16;

static __device__ __forceinline__ unsigned short f2bf(float f) {
    union { float f; unsigned int u; } x; x.f = f;
    unsigned int u = x.u;
    unsigned int r = (u + 0x7FFFu + ((u >> 16) & 1u)) >> 16;   // RNE
    return (unsigned short)r;
}
static __device__ __forceinline__ float bf2f(unsigned short u) {
    union { unsigned int u; float f; } x; x.u = ((unsigned int)u) << 16;
    return x.f;
}
static __device__ __forceinline__ float sigm(float x) { return 1.f / (1.f + __expf(-x)); }
static __device__ __forceinline__ float tanh_(float x) { return 2.f / (1.f + __expf(-2.f * x)) - 1.f; }

static __device__ __forceinline__ void gload_lds16(const void* g, void* l) {
    __builtin_amdgcn_global_load_lds(
        (const __attribute__((address_space(1))) unsigned int*)g,
        (__attribute__((address_space(3))) unsigned int*)l, 16, 0, 0);
}

// ---------------- embedding gather -> bf16 [32][256][512] (row = b*256+t) ----------------
__global__ __launch_bounds__(256) void gather_kernel(const int* __restrict__ x,
                                                     const float* __restrict__ emb,
                                                     unsigned short* __restrict__ ebf) {
    const int bt = blockIdx.x;
    const int tok = x[bt];
    const float* src = emb + (size_t)tok * E_;
    const int c = threadIdx.x * 2;
    float2 v = *(const float2*)(src + c);
    unsigned int pk = (unsigned int)f2bf(v.x) | ((unsigned int)f2bf(v.y) << 16);
    *(unsigned int*)(ebf + (size_t)bt * E_ + c) = pk;
}

// ---------------- weight pack -> 32x32x16 B-fragment-major bf16 ----------------
// frag (tau32, kk16): lane l: col = colmap(tau32*32 + (l&31)), k = kk16*16 + (l>>5)*8 + j.
// dst[(fid*64+l)*8], fid = tau32*KK16 + kk16.
// PERM=1: vcol -> actual col g*1024 + wc*16 + uu  (vcol = wc*64 + g*16 + uu)
__global__ __launch_bounds__(256) void pack_frag(const float* __restrict__ src,
                                                 unsigned short* __restrict__ dst,
                                                 int KK16, int PERM) {
    const int fid = blockIdx.x * 4 + (threadIdx.x >> 6);
    const int lane = threadIdx.x & 63;
    const int tau = fid / KK16;
    const int kk = fid - tau * KK16;
    int vcol = tau * 32 + (lane & 31);
    int col;
    if (PERM) {
        int wc = vcol >> 6, g = (vcol >> 4) & 3, uu = vcol & 15;
        col = g * 1024 + wc * 16 + uu;
    } else col = vcol;
    const int k0 = kk * 16 + ((lane >> 5) << 3);
    unsigned int pk[4];
#pragma unroll
    for (int jj = 0; jj < 4; ++jj) {
        float v0 = src[(size_t)(k0 + jj * 2) * G4 + col];
        float v1 = src[(size_t)(k0 + jj * 2 + 1) * G4 + col];
        pk[jj] = (unsigned int)f2bf(v0) | ((unsigned int)f2bf(v1) << 16);
    }
    uint4 o; o.x = pk[0]; o.y = pk[1]; o.z = pk[2]; o.w = pk[3];
    *(uint4*)(dst + ((size_t)fid * 64 + lane) * 8) = o;
}

// ---------------- Xw GEMM: C[dir][row][4096] = A[row][K] @ W + bias (bf16 out) ----------------
template <int KK16>
__global__ __launch_bounds__(256) void gemm_xw(
    const unsigned short* __restrict__ Abase, unsigned long long adstride,
    const unsigned short* __restrict__ P0, const unsigned short* __restrict__ P1,
    const float* __restrict__ bias0, const float* __restrict__ bias1,
    unsigned short* __restrict__ C)
{
    constexpr int K = KK16 * 16;
    constexpr int NT = KK16 / 4;                   // BK=64 tiles
    __shared__ unsigned short alds[2][128 * 64];   // 2 x 16KB
    const int bm = blockIdx.x, bn = blockIdx.y, dir = blockIdx.z;
    const unsigned short* A = Abase + (size_t)dir * adstride;
    const unsigned short* P = dir ? P1 : P0;
    const float* bias = dir ? bias1 : bias0;
    unsigned short* Cd = C + (size_t)dir * SROWS * G4;
    const int tid = threadIdx.x, w = tid >> 6, lane = tid & 63;
    const int l31 = lane & 31, lhi = lane >> 5;

    f32x16 acc0, acc1;
#pragma unroll
    for (int i = 0; i < 16; ++i) { acc0[i] = 0.f; acc1[i] = 0.f; }

    const int swz_in = (lane & 7) * 16;

#define STAGE(buf, kt)                                                                     \
    {                                                                                      \
        _Pragma("unroll")                                                                  \
        for (int i = 0; i < 4; ++i) {                                                      \
            const int idx = w * 4 + i;                                                     \
            const int row = idx * 8 + (lane >> 3);                                         \
            const int inrow = swz_in ^ ((row & 7) << 4);                                   \
            const unsigned short* src = A + (size_t)(bm * 128 + row) * K + (kt) * 64 + (inrow >> 1); \
            gload_lds16(src, (char*)&alds[buf][0] + idx * 1024);                           \
        }                                                                                  \
    }

    STAGE(0, 0);
    __syncthreads();
    for (int kt = 0; kt < NT; ++kt) {
        if (kt + 1 < NT) STAGE((kt + 1) & 1, kt + 1);
        const char* ab = (const char*)&alds[kt & 1][0];
        const int arow = w * 32 + l31;
#pragma unroll
        for (int kk = 0; kk < 4; ++kk) {
            const int koff = (kk * 32 + lhi * 16) ^ ((arow & 7) << 4);
            short8 af = *(const short8*)(ab + arow * 128 + koff);
            short8 bf0 = *(const short8*)(P + ((size_t)((bn * 2 + 0) * KK16 + kt * 4 + kk) * 64 + lane) * 8);
            short8 bf1 = *(const short8*)(P + ((size_t)((bn * 2 + 1) * KK16 + kt * 4 + kk) * 64 + lane) * 8);
            acc0 = __builtin_amdgcn_mfma_f32_32x32x16_bf16(af, bf0, acc0, 0, 0, 0);
            acc1 = __builtin_amdgcn_mfma_f32_32x32x16_bf16(af, bf1, acc1, 0, 0, 0);
        }
        __syncthreads();
    }
#undef STAGE
    const int col0 = bn * 64 + l31;
    const int col1 = col0 + 32;
    const float bv0 = bias[col0], bv1 = bias[col1];
#pragma unroll
    for (int reg = 0; reg < 16; ++reg) {
        const int r = (reg & 3) + 8 * (reg >> 2) + 4 * lhi;
        const size_t row = (size_t)bm * 128 + w * 32 + r;
        Cd[row * G4 + col0] = f2bf(acc0[reg] + bv0);
        Cd[row * G4 + col1] = f2bf(acc1[reg] + bv1);
    }
}

// ---------------- persistent scan: one layer, both dirs ----------------
// 64 WGs x 512 thr: dir = wg>>5, wq = wg&31 (32 ucols / 128 gatecols).
// Wave w: ct = w&3 (col-tile of 32 gatecols), kh = w>>2 (K-half of 512).
// Weights: wf[32] = 128 VGPR/wave. h exchange via relaxed agent atomics (sc0/sc1).
template <int LAYER>
__global__ __launch_bounds__(512, 2) void scan_kernel(
    const unsigned short* __restrict__ puF, const unsigned short* __restrict__ puB,
    const unsigned short* __restrict__ Xw,     // [2][SROWS][4096] (L0 row=b*256+t, L1 row=s*32+b)
    const int* __restrict__ xtok,
    unsigned short* __restrict__ hcomm,        // [2 phase][2 dir][32][1024] bf16
    float* __restrict__ hstate, float* __restrict__ cstate,
    unsigned short* __restrict__ out0,         // [2][SROWS][1024] bf16
    unsigned int* __restrict__ flags)          // [2 dir][32] step counters
{
    constexpr int PH = (LAYER == 0) ? 0 : 1;
    __shared__ unsigned short h_lds[32768];        // 64KB: [32 rows][2048B], XOR-swizzled
    __shared__ float zbuf[8][32][33];              // 33.8KB

    const int wg = blockIdx.x, dir = wg >> 5, wq = wg & 31;
    const int tid = threadIdx.x;
    const int w = tid >> 6, lane = tid & 63;
    const int ct = w & 3, kh = w >> 2;
    const int l31 = lane & 31, lhi = lane >> 5;
    const unsigned short* pu = dir ? puB : puF;

    // ---- weight preload: 32 frags (tau = wq*4+ct, kk16 = kh*32 + kkL) ----
    short8 wf[32];
    {
        const int tau = wq * 4 + ct;
#pragma unroll
        for (int kkL = 0; kkL < 32; ++kkL)
            wf[kkL] = *(const short8*)(pu + (((size_t)tau * 64 + kh * 32 + kkL) * 64 + lane) * 8);
    }

    // ---- cell ids: thread owns (b, uu0) and (b, uu0+1); uu0 = local ucol ----
    const int b = tid >> 4, up = tid & 15, uu0 = up * 2;
    const int ch = up >> 3;                    // uu0>>4
    const int um = (up & 7) * 2;               // uu0&15
    const int ucol = wq * 32 + uu0;
    const int sbase = (dir * 32 + b) * U_ + ucol;
    float c0 = cstate[sbase], c1 = cstate[sbase + 1];
    float h0 = hstate[sbase], h1 = hstate[sbase + 1];
    float o0 = 0.f, o1 = 0.f;
    const unsigned short* xwbase = Xw + (size_t)dir * SROWS * G4;

    // staging ids: 16 x u64 per thread, contiguous granules
    const int sthi = tid >> 8;                 // 0/1
    const int inrow = (tid & 255) * 8;         // byte offset in 2048B row

    for (int s = 0; s < TS; ++s) {
        const int tcol = dir ? (TS - s) : s;
        // -- stage h[phase] -> LDS via coherent (sc0/sc1) loads --
        {
            const char* hrd = (const char*)(hcomm + (size_t)((s + PH) & 1) * (2 * 32 * U_) + dir * 32 * U_);
#pragma unroll
            for (int j = 0; j < 16; ++j) {
                const int r = j * 2 + sthi;
                unsigned long long v = __hip_atomic_load(
                    (const unsigned long long*)(hrd + r * 2048 + inrow),
                    __ATOMIC_RELAXED, __HIP_MEMORY_SCOPE_AGENT);
                *(unsigned long long*)((char*)h_lds + r * 2048 + (inrow ^ ((r & 7) << 4))) = v;
            }
        }
        // -- Xw + mask prefetch (regular cached loads; written pre-dispatch) --
        const size_t xr = (LAYER == 0) ? ((size_t)b * T_ + tcol) : ((size_t)s * 32 + b);
        const unsigned short* xp = xwbase + xr * G4 + ucol;
        const unsigned int xwi = *(const unsigned int*)(xp);
        const unsigned int xwf = *(const unsigned int*)(xp + 1024);
        const unsigned int xwg = *(const unsigned int*)(xp + 2048);
        const unsigned int xwo = *(const unsigned int*)(xp + 3072);
        const int m = xtok[b * T_ + tcol] != 0;
        __syncthreads();                       // h_lds ready

        // -- MFMA: h @ U (col-tile ct, K-half kh): 32 x 32x32x16 --
        f32x16 acc;
#pragma unroll
        for (int i = 0; i < 16; ++i) acc[i] = 0.f;
        {
            const char* hb = (const char*)h_lds + l31 * 2048;
            const int swz = (l31 & 7) << 4;
#pragma unroll
            for (int kkL = 0; kkL < 32; ++kkL) {
                const int koff = (((kh * 32 + kkL) * 32) + lhi * 16) ^ swz;
                short8 af = *(const short8*)(hb + koff);
                acc = __builtin_amdgcn_mfma_f32_32x32x16_bf16(af, wf[kkL], acc, 0, 0, 0);
            }
        }
        // D: col = l31, row = (reg&3)+8*(reg>>2)+4*lhi
#pragma unroll
        for (int reg = 0; reg < 16; ++reg) {
            const int zr = (reg & 3) + 8 * (reg >> 2) + 4 * lhi;
            zbuf[w][zr][l31] = acc[reg];
        }
        __syncthreads();

        // -- elementwise cell (2 cells/thread) --
        {
            float z[4][2];
#pragma unroll
            for (int g = 0; g < 4; ++g)
#pragma unroll
                for (int j = 0; j < 2; ++j) {
                    const int lv = ch * 64 + g * 16 + um + j;
                    const int ctl = lv >> 5, c32 = lv & 31;
                    z[g][j] = zbuf[ctl][b][c32] + zbuf[4 + ctl][b][c32];
                }
            z[0][0] += bf2f((unsigned short)(xwi & 0xffff)); z[0][1] += bf2f((unsigned short)(xwi >> 16));
            z[1][0] += bf2f((unsigned short)(xwf & 0xffff)); z[1][1] += bf2f((unsigned short)(xwf >> 16));
            z[2][0] += bf2f((unsigned short)(xwg & 0xffff)); z[2][1] += bf2f((unsigned short)(xwg >> 16));
            z[3][0] += bf2f((unsigned short)(xwo & 0xffff)); z[3][1] += bf2f((unsigned short)(xwo >> 16));

            float cn = sigm(z[1][0]) * c0 + sigm(z[0][0]) * tanh_(z[2][0]);
            float hn = sigm(z[3][0]) * tanh_(cn);
            if (m) { c0 = cn; h0 = hn; o0 = hn; }
            cn = sigm(z[1][1]) * c1 + sigm(z[0][1]) * tanh_(z[2][1]);
            hn = sigm(z[3][1]) * tanh_(cn);
            if (m) { c1 = cn; h1 = hn; o1 = hn; }

            // h publish: coherent write-through (2 bf16 per thread)
            unsigned short* hwr = hcomm + (size_t)((s + PH + 1) & 1) * (2 * 32 * U_);
            __hip_atomic_store((unsigned int*)(hwr + sbase),
                               (unsigned int)f2bf(h0) | ((unsigned int)f2bf(h1) << 16),
                               __ATOMIC_RELAXED, __HIP_MEMORY_SCOPE_AGENT);
            const size_t orow = (size_t)dir * SROWS + (size_t)s * 32 + b;
            *(unsigned int*)(out0 + orow * U_ + ucol) =
                (unsigned int)f2bf(o0) | ((unsigned int)f2bf(o1) << 16);
        }
        __syncthreads();                       // drains each thread's vmcnt (h stores acked at L3)

        // -- flag publish + coalesced poll (no cache maintenance, no hot counter) --
        if (tid == 0)
            __hip_atomic_store(flags + dir * 32 + wq, (unsigned int)(s + 1),
                               __ATOMIC_RELAXED, __HIP_MEMORY_SCOPE_AGENT);
        if (tid < 32) {
            while (true) {
                unsigned int v = __hip_atomic_load(flags + dir * 32 + tid,
                                                   __ATOMIC_RELAXED, __HIP_MEMORY_SCOPE_AGENT);
                if (__all((int)v > s)) break;
                __builtin_amdgcn_s_sleep(1);
            }
        }
        __syncthreads();
    }
    hstate[sbase] = h0; hstate[sbase + 1] = h1;
    cstate[sbase] = c0; cstate[sbase + 1] = c1;
}

// ---------------- layernorm (per row of 1024) ----------------
__global__ __launch_bounds__(256) void ln_kernel(const unsigned short* __restrict__ in,
                                                 const float* __restrict__ gamma,
                                                 const float* __restrict__ beta,
                                                 unsigned short* __restrict__ outbf,
                                                 float* __restrict__ outf,
                                                 int final_) {
    const int r = blockIdx.x;          // 0..8159 (= s*32+b)
    const int dir = blockIdx.y;
    const int s = r >> 5, bb = r & 31;
    const size_t rowoff = ((size_t)dir * SROWS + r) * U_;
    const int tid = threadIdx.x;
    const int c = tid * 4;

    uint2 raw = *(const uint2*)(in + rowoff + c);
    float v0 = bf2f((unsigned short)(raw.x & 0xffff));
    float v1 = bf2f((unsigned short)(raw.x >> 16));
    float v2 = bf2f((unsigned short)(raw.y & 0xffff));
    float v3 = bf2f((unsigned short)(raw.y >> 16));

    float sum = v0 + v1 + v2 + v3;
    float sq = v0 * v0 + v1 * v1 + v2 * v2 + v3 * v3;
#pragma unroll
    for (int off = 32; off > 0; off >>= 1) {
        sum += __shfl_down(sum, off);
        sq  += __shfl_down(sq, off);
    }
    __shared__ float red[8];
    __shared__ float stats[2];
    const int wv = tid >> 6;
    if ((tid & 63) == 0) { red[wv] = sum; red[4 + wv] = sq; }
    __syncthreads();
    if (tid == 0) {
        float S = red[0] + red[1] + red[2] + red[3];
        float Q = red[4] + red[5] + red[6] + red[7];
        float mu = S * (1.f / 1024.f);
        float var = Q * (1.f / 1024.f) - mu * mu;
        stats[0] = mu;
        stats[1] = rsqrtf(var + 1e-3f);
    }
    __syncthreads();
    const float mu = stats[0], inv = stats[1];
    float y0 = (v0 - mu) * inv * gamma[c]     + beta[c];
    float y1 = (v1 - mu) * inv * gamma[c + 1] + beta[c + 1];
    float y2 = (v2 - mu) * inv * gamma[c + 2] + beta[c + 2];
    float y3 = (v3 - mu) * inv * gamma[c + 3] + beta[c + 3];

    if (!final_) {
        uint2 o;
        o.x = (unsigned int)f2bf(y0) | ((unsigned int)f2bf(y1) << 16);
        o.y = (unsigned int)f2bf(y2) | ((unsigned int)f2bf(y3) << 16);
        *(uint2*)(outbf + rowoff + c) = o;
    } else {
        const size_t tIdx = dir ? (size_t)(254 - s) : (size_t)s;
        const size_t o = (size_t)dir * ROWS * U_ + ((size_t)bb * TS + tIdx) * U_ + c;
        float4 y; y.x = y0; y.y = y1; y.z = y2; y.w = y3;
        *(float4*)(outf + o) = y;
    }
}

// ---------------- host ----------------
extern "C" void kernel_launch(void* const* d_in, const int* in_sizes, int n_in,
                              void* d_out, int out_size, void* d_ws, size_t ws_size,
                              hipStream_t stream) {
    (void)in_sizes; (void)n_in; (void)out_size; (void)ws_size;
    const int*   x   = (const int*)d_in[0];
    const float* emb = (const float*)d_in[1];
    const float* fW0 = (const float*)d_in[2];
    const float* fU0 = (const float*)d_in[3];
    const float* fb0 = (const float*)d_in[4];
    const float* bW0 = (const float*)d_in[5];
    const float* bU0 = (const float*)d_in[6];
    const float* bb0 = (const float*)d_in[7];
    const float* g0  = (const float*)d_in[8];
    const float* be0 = (const float*)d_in[9];
    const float* fW1 = (const float*)d_in[10];
    const float* fU1 = (const float*)d_in[11];
    const float* fb1 = (const float*)d_in[12];
    const float* bW1 = (const float*)d_in[13];
    const float* bU1 = (const float*)d_in[14];
    const float* bb1 = (const float*)d_in[15];
    const float* g1  = (const float*)d_in[16];
    const float* be1 = (const float*)d_in[17];

    // ---- aliased workspace layout (total ~219 MB) ----
    const size_t MB8  = 8388608;
    const size_t MB4  = 4194304;
    char* ws = (char*)d_ws;
    // S0: 32 MiB — ebf|pu0f|pu0b|pw0f|pw0b, all dead after scan<0>; reused as x1
    char* S0 = ws;
    unsigned short* ebf  = (unsigned short*)(S0);
    unsigned short* pu0f = (unsigned short*)(S0 + MB8);
    unsigned short* pu0b = (unsigned short*)(S0 + 2 * MB8);
    unsigned short* pw0f = (unsigned short*)(S0 + 3 * MB8);
    unsigned short* pw0b = (unsigned short*)(S0 + 3 * MB8 + MB4);
    unsigned short* x1   = (unsigned short*)(S0);            // alias (after scan<0>)
    // S1: 16 MiB — pw1f|pw1b (dead after gemm1) -> pu1f|pu1b
    char* S1 = ws + 4 * MB8;
    unsigned short* pw1f = (unsigned short*)(S1);
    unsigned short* pw1b = (unsigned short*)(S1 + MB8);
    unsigned short* pu1f = (unsigned short*)(S1);            // alias (after gemm1)
    unsigned short* pu1b = (unsigned short*)(S1 + MB8);
    // out0: 32 MiB
    unsigned short* out0 = (unsigned short*)(ws + 6 * MB8);
    // Xw: 128 MiB
    unsigned short* Xw   = (unsigned short*)(ws + 10 * MB8);
    // state
    char* stateblob = ws + 26 * MB8;
    unsigned short* hcomm = (unsigned short*)stateblob;            // 262144 B
    float* hstate = (float*)(stateblob + 262144);
    float* cstate = (float*)(stateblob + 524288);
    unsigned int* flags = (unsigned int*)(stateblob + 786432);     // 2 layers x 64

    hipMemsetAsync(stateblob, 0, 786432 + 1024, stream);

    gather_kernel<<<dim3(B_ * T_), 256, 0, stream>>>(x, emb, ebf);

    pack_frag<<<dim3(128 * 64 / 4), 256, 0, stream>>>(fU0, pu0f, 64, 1);
    pack_frag<<<dim3(128 * 64 / 4), 256, 0, stream>>>(bU0, pu0b, 64, 1);
    pack_frag<<<dim3(128 * 32 / 4), 256, 0, stream>>>(fW0, pw0f, 32, 0);
    pack_frag<<<dim3(128 * 32 / 4), 256, 0, stream>>>(bW0, pw0b, 32, 0);
    pack_frag<<<dim3(128 * 64 / 4), 256, 0, stream>>>(fW1, pw1f, 64, 0);
    pack_frag<<<dim3(128 * 64 / 4), 256, 0, stream>>>(bW1, pw1b, 64, 0);

    // Xw0 = e @ W0 + b0  (rows = b*256+t, 8192)
    gemm_xw<32><<<dim3(64, 64, 2), 256, 0, stream>>>(ebf, 0ull, pw0f, pw0b, fb0, bb0, Xw);
    scan_kernel<0><<<dim3(64), 512, 0, stream>>>(pu0f, pu0b, Xw, x, hcomm, hstate, cstate, out0, flags);
    ln_kernel<<<dim3(ROWS, 2), 256, 0, stream>>>(out0, g0, be0, x1, nullptr, 0);
    // Xw1 = x1 @ W1 + b1  (rows = s*32+b)
    gemm_xw<64><<<dim3(64, 64, 2), 256, 0, stream>>>(x1, (unsigned long long)SROWS * U_, pw1f, pw1b, fb1, bb1, Xw);
    pack_frag<<<dim3(128 * 64 / 4), 256, 0, stream>>>(fU1, pu1f, 64, 1);
    pack_frag<<<dim3(128 * 64 / 4), 256, 0, stream>>>(bU1, pu1b, 64, 1);
    scan_kernel<1><<<dim3(64), 512, 0, stream>>>(pu1f, pu1b, Xw, x, hcomm, hstate, cstate, out0, flags + 64);
    ln_kernel<<<dim3(ROWS, 2), 256, 0, stream>>>(out0, g1, be1, nullptr, (float*)d_out, 1);
}

// Round 6
// 2490.384 us; speedup vs baseline: 5.4005x; 1.6689x over previous
//
#include <hip/hip_runtime.h>
#include <hip/hip_bf16.h>

// ELMo: 2-layer bidirectional masked LSTM + LN. B=32, T=256 (255 steps), E=512, U=1024.
// R6: R4 topology (64 WGs, placement-agnostic L3 communication via agent-scope ops) with
// h-staging done as 8 batched inline-asm sc0/sc1 dwordx4 loads + ONE vmcnt(0) wait
// (R4's per-element atomic loads serialized ~16 L3 round trips per step).

#define B_  32
#define T_  256
#define TS  255
#define E_  512
#define U_  1024
#define G4  4096
#define ROWS 8160        // TS*B_
#define SROWS 8192       // padded per-dir row stride for out0/x1/Xw

typedef __attribute__((ext_vector_type(8))) short short8;
typedef __attribute__((ext_vector_type(16))) float f32x16;

static __device__ __forceinline__ unsigned short f2bf(float f) {
    union { float f; unsigned int u; } x; x.f = f;
    unsigned int u = x.u;
    unsigned int r = (u + 0x7FFFu + ((u >> 16) & 1u)) >> 16;   // RNE
    return (unsigned short)r;
}
static __device__ __forceinline__ float bf2f(unsigned short u) {
    union { unsigned int u; float f; } x; x.u = ((unsigned int)u) << 16;
    return x.f;
}
static __device__ __forceinline__ float sigm(float x) { return 1.f / (1.f + __expf(-x)); }
static __device__ __forceinline__ float tanh_(float x) { return 2.f / (1.f + __expf(-2.f * x)) - 1.f; }

static __device__ __forceinline__ void gload_lds16(const void* g, void* l) {
    __builtin_amdgcn_global_load_lds(
        (const __attribute__((address_space(1))) unsigned int*)g,
        (__attribute__((address_space(3))) unsigned int*)l, 16, 0, 0);
}

// ---------------- embedding gather -> bf16 [32][256][512] (row = b*256+t) ----------------
__global__ __launch_bounds__(256) void gather_kernel(const int* __restrict__ x,
                                                     const float* __restrict__ emb,
                                                     unsigned short* __restrict__ ebf) {
    const int bt = blockIdx.x;
    const int tok = x[bt];
    const float* src = emb + (size_t)tok * E_;
    const int c = threadIdx.x * 2;
    float2 v = *(const float2*)(src + c);
    unsigned int pk = (unsigned int)f2bf(v.x) | ((unsigned int)f2bf(v.y) << 16);
    *(unsigned int*)(ebf + (size_t)bt * E_ + c) = pk;
}

// ---------------- weight pack -> 32x32x16 B-fragment-major bf16 ----------------
__global__ __launch_bounds__(256) void pack_frag(const float* __restrict__ src,
                                                 unsigned short* __restrict__ dst,
                                                 int KK16, int PERM) {
    const int fid = blockIdx.x * 4 + (threadIdx.x >> 6);
    const int lane = threadIdx.x & 63;
    const int tau = fid / KK16;
    const int kk = fid - tau * KK16;
    int vcol = tau * 32 + (lane & 31);
    int col;
    if (PERM) {
        int wc = vcol >> 6, g = (vcol >> 4) & 3, uu = vcol & 15;
        col = g * 1024 + wc * 16 + uu;
    } else col = vcol;
    const int k0 = kk * 16 + ((lane >> 5) << 3);
    unsigned int pk[4];
#pragma unroll
    for (int jj = 0; jj < 4; ++jj) {
        float v0 = src[(size_t)(k0 + jj * 2) * G4 + col];
        float v1 = src[(size_t)(k0 + jj * 2 + 1) * G4 + col];
        pk[jj] = (unsigned int)f2bf(v0) | ((unsigned int)f2bf(v1) << 16);
    }
    uint4 o; o.x = pk[0]; o.y = pk[1]; o.z = pk[2]; o.w = pk[3];
    *(uint4*)(dst + ((size_t)fid * 64 + lane) * 8) = o;
}

// ---------------- Xw GEMM: C[dir][row][4096] = A[row][K] @ W + bias (bf16 out) ----------------
template <int KK16>
__global__ __launch_bounds__(256) void gemm_xw(
    const unsigned short* __restrict__ Abase, unsigned long long adstride,
    const unsigned short* __restrict__ P0, const unsigned short* __restrict__ P1,
    const float* __restrict__ bias0, const float* __restrict__ bias1,
    unsigned short* __restrict__ C)
{
    constexpr int K = KK16 * 16;
    constexpr int NT = KK16 / 4;                   // BK=64 tiles
    __shared__ unsigned short alds[2][128 * 64];   // 2 x 16KB
    const int bm = blockIdx.x, bn = blockIdx.y, dir = blockIdx.z;
    const unsigned short* A = Abase + (size_t)dir * adstride;
    const unsigned short* P = dir ? P1 : P0;
    const float* bias = dir ? bias1 : bias0;
    unsigned short* Cd = C + (size_t)dir * SROWS * G4;
    const int tid = threadIdx.x, w = tid >> 6, lane = tid & 63;
    const int l31 = lane & 31, lhi = lane >> 5;

    f32x16 acc0, acc1;
#pragma unroll
    for (int i = 0; i < 16; ++i) { acc0[i] = 0.f; acc1[i] = 0.f; }

    const int swz_in = (lane & 7) * 16;

#define STAGE(buf, kt)                                                                     \
    {                                                                                      \
        _Pragma("unroll")                                                                  \
        for (int i = 0; i < 4; ++i) {                                                      \
            const int idx = w * 4 + i;                                                     \
            const int row = idx * 8 + (lane >> 3);                                         \
            const int inrow = swz_in ^ ((row & 7) << 4);                                   \
            const unsigned short* src = A + (size_t)(bm * 128 + row) * K + (kt) * 64 + (inrow >> 1); \
            gload_lds16(src, (char*)&alds[buf][0] + idx * 1024);                           \
        }                                                                                  \
    }

    STAGE(0, 0);
    __syncthreads();
    for (int kt = 0; kt < NT; ++kt) {
        if (kt + 1 < NT) STAGE((kt + 1) & 1, kt + 1);
        const char* ab = (const char*)&alds[kt & 1][0];
        const int arow = w * 32 + l31;
#pragma unroll
        for (int kk = 0; kk < 4; ++kk) {
            const int koff = (kk * 32 + lhi * 16) ^ ((arow & 7) << 4);
            short8 af = *(const short8*)(ab + arow * 128 + koff);
            short8 bf0 = *(const short8*)(P + ((size_t)((bn * 2 + 0) * KK16 + kt * 4 + kk) * 64 + lane) * 8);
            short8 bf1 = *(const short8*)(P + ((size_t)((bn * 2 + 1) * KK16 + kt * 4 + kk) * 64 + lane) * 8);
            acc0 = __builtin_amdgcn_mfma_f32_32x32x16_bf16(af, bf0, acc0, 0, 0, 0);
            acc1 = __builtin_amdgcn_mfma_f32_32x32x16_bf16(af, bf1, acc1, 0, 0, 0);
        }
        __syncthreads();
    }
#undef STAGE
    const int col0 = bn * 64 + l31;
    const int col1 = col0 + 32;
    const float bv0 = bias[col0], bv1 = bias[col1];
#pragma unroll
    for (int reg = 0; reg < 16; ++reg) {
        const int r = (reg & 3) + 8 * (reg >> 2) + 4 * lhi;
        const size_t row = (size_t)bm * 128 + w * 32 + r;
        Cd[row * G4 + col0] = f2bf(acc0[reg] + bv0);
        Cd[row * G4 + col1] = f2bf(acc1[reg] + bv1);
    }
}

// ---------------- persistent scan: one layer, both dirs ----------------
// 64 WGs x 512 thr: dir = wg>>5, wq = wg&31 (32 ucols / 128 gatecols).
// Wave w: ct = w&3 (col-tile of 32 gatecols), kh = w>>2 (K-half of 512).
// Weights: wf[32] = 128 VGPR/wave. h exchange via L3 (sc0/sc1), batched single-wait loads.
template <int LAYER>
__global__ __launch_bounds__(512, 2) void scan_kernel(
    const unsigned short* __restrict__ puF, const unsigned short* __restrict__ puB,
    const unsigned short* __restrict__ Xw,     // [2][SROWS][4096] (L0 row=b*256+t, L1 row=s*32+b)
    const int* __restrict__ xtok,
    unsigned short* __restrict__ hcomm,        // [2 phase][2 dir][32][1024] bf16
    float* __restrict__ hstate, float* __restrict__ cstate,
    unsigned short* __restrict__ out0,         // [2][SROWS][1024] bf16
    unsigned int* __restrict__ flags)          // [2 dir][32] step counters
{
    constexpr int PH = (LAYER == 0) ? 0 : 1;
    __shared__ unsigned short h_lds[32768];        // 64KB: [32 rows][2048B], XOR-swizzled
    __shared__ float zbuf[8][32][33];              // 33.8KB

    const int wg = blockIdx.x, dir = wg >> 5, wq = wg & 31;
    const int tid = threadIdx.x;
    const int w = tid >> 6, lane = tid & 63;
    const int ct = w & 3, kh = w >> 2;
    const int l31 = lane & 31, lhi = lane >> 5;
    const unsigned short* pu = dir ? puB : puF;

    // ---- weight preload: 32 frags (tau = wq*4+ct, kk16 = kh*32 + kkL) ----
    short8 wf[32];
    {
        const int tau = wq * 4 + ct;
#pragma unroll
        for (int kkL = 0; kkL < 32; ++kkL)
            wf[kkL] = *(const short8*)(pu + (((size_t)tau * 64 + kh * 32 + kkL) * 64 + lane) * 8);
    }

    // ---- cell ids: thread owns (b, uu0) and (b, uu0+1) ----
    const int b = tid >> 4, up = tid & 15, uu0 = up * 2;
    const int ch = up >> 3;
    const int um = (up & 7) * 2;
    const int ucol = wq * 32 + uu0;
    const int sbase = (dir * 32 + b) * U_ + ucol;
    float c0 = cstate[sbase], c1 = cstate[sbase + 1];
    float h0 = hstate[sbase], h1 = hstate[sbase + 1];
    float o0 = 0.f, o1 = 0.f;
    const unsigned short* xwbase = Xw + (size_t)dir * SROWS * G4;

    for (int s = 0; s < TS; ++s) {
        const int tcol = dir ? (TS - s) : s;
        // -- stage h[phase] -> LDS: 8 batched sc0/sc1 dwordx4 loads, ONE vmcnt wait --
        {
            const char* hrd = (const char*)(hcomm +
                ((size_t)((s + PH) & 1) * 2 + dir) * (32 * U_));
            uint4 hv[8];
#pragma unroll
            for (int j = 0; j < 8; ++j) {
                const void* src = hrd + ((size_t)j * 512 + tid) * 16;
                asm volatile("global_load_dwordx4 %0, %1, off sc0 sc1"
                             : "=v"(hv[j]) : "v"(src));
            }
            asm volatile("s_waitcnt vmcnt(0)" ::: "memory");
            __builtin_amdgcn_sched_barrier(0);
#pragma unroll
            for (int j = 0; j < 8; ++j) {
                const int gidx = j * 512 + tid;
                const int r = gidx >> 7;
                const int off = (gidx & 127) * 16;
                *(uint4*)((char*)h_lds + r * 2048 + (off ^ ((r & 7) << 4))) = hv[j];
            }
        }
        // -- Xw + mask prefetch (plain cached loads; written pre-dispatch) --
        const size_t xr = (LAYER == 0) ? ((size_t)b * T_ + tcol) : ((size_t)s * 32 + b);
        const unsigned short* xp = xwbase + xr * G4 + ucol;
        const unsigned int xwi = *(const unsigned int*)(xp);
        const unsigned int xwf = *(const unsigned int*)(xp + 1024);
        const unsigned int xwg = *(const unsigned int*)(xp + 2048);
        const unsigned int xwo = *(const unsigned int*)(xp + 3072);
        const int m = xtok[b * T_ + tcol] != 0;
        __syncthreads();                       // h_lds ready

        // -- MFMA: h @ U (col-tile ct, K-half kh): 32 x 32x32x16 --
        f32x16 acc;
#pragma unroll
        for (int i = 0; i < 16; ++i) acc[i] = 0.f;
        {
            const char* hb = (const char*)h_lds + l31 * 2048;
            const int swz = (l31 & 7) << 4;
#pragma unroll
            for (int kkL = 0; kkL < 32; ++kkL) {
                const int koff = (((kh * 32 + kkL) * 32) + lhi * 16) ^ swz;
                short8 af = *(const short8*)(hb + koff);
                acc = __builtin_amdgcn_mfma_f32_32x32x16_bf16(af, wf[kkL], acc, 0, 0, 0);
            }
        }
        // D: col = l31, row = (reg&3)+8*(reg>>2)+4*lhi
#pragma unroll
        for (int reg = 0; reg < 16; ++reg) {
            const int zr = (reg & 3) + 8 * (reg >> 2) + 4 * lhi;
            zbuf[w][zr][l31] = acc[reg];
        }
        __syncthreads();

        // -- elementwise cell (2 cells/thread) --
        {
            float z[4][2];
#pragma unroll
            for (int g = 0; g < 4; ++g)
#pragma unroll
                for (int j = 0; j < 2; ++j) {
                    const int lv = ch * 64 + g * 16 + um + j;
                    const int ctl = lv >> 5, c32 = lv & 31;
                    z[g][j] = zbuf[ctl][b][c32] + zbuf[4 + ctl][b][c32];
                }
            z[0][0] += bf2f((unsigned short)(xwi & 0xffff)); z[0][1] += bf2f((unsigned short)(xwi >> 16));
            z[1][0] += bf2f((unsigned short)(xwf & 0xffff)); z[1][1] += bf2f((unsigned short)(xwf >> 16));
            z[2][0] += bf2f((unsigned short)(xwg & 0xffff)); z[2][1] += bf2f((unsigned short)(xwg >> 16));
            z[3][0] += bf2f((unsigned short)(xwo & 0xffff)); z[3][1] += bf2f((unsigned short)(xwo >> 16));

            float cn = sigm(z[1][0]) * c0 + sigm(z[0][0]) * tanh_(z[2][0]);
            float hn = sigm(z[3][0]) * tanh_(cn);
            if (m) { c0 = cn; h0 = hn; o0 = hn; }
            cn = sigm(z[1][1]) * c1 + sigm(z[0][1]) * tanh_(z[2][1]);
            hn = sigm(z[3][1]) * tanh_(cn);
            if (m) { c1 = cn; h1 = hn; o1 = hn; }

            // h publish: coherent write-through (2 bf16 per thread)
            unsigned short* hwr = hcomm + (size_t)((s + PH + 1) & 1) * (2 * 32 * U_);
            __hip_atomic_store((unsigned int*)(hwr + sbase),
                               (unsigned int)f2bf(h0) | ((unsigned int)f2bf(h1) << 16),
                               __ATOMIC_RELAXED, __HIP_MEMORY_SCOPE_AGENT);
            const size_t orow = (size_t)dir * SROWS + (size_t)s * 32 + b;
            *(unsigned int*)(out0 + orow * U_ + ucol) =
                (unsigned int)f2bf(o0) | ((unsigned int)f2bf(o1) << 16);
        }
        __syncthreads();                       // drains each thread's vmcnt (h stores acked at L3)

        // -- flag publish + coalesced poll --
        if (tid == 0)
            __hip_atomic_store(flags + dir * 32 + wq, (unsigned int)(s + 1),
                               __ATOMIC_RELAXED, __HIP_MEMORY_SCOPE_AGENT);
        if (tid < 32) {
            while (true) {
                unsigned int v = __hip_atomic_load(flags + dir * 32 + tid,
                                                   __ATOMIC_RELAXED, __HIP_MEMORY_SCOPE_AGENT);
                if (__all((int)v > s)) break;
                __builtin_amdgcn_s_sleep(1);
            }
        }
        __syncthreads();
    }
    hstate[sbase] = h0; hstate[sbase + 1] = h1;
    cstate[sbase] = c0; cstate[sbase + 1] = c1;
}

// ---------------- layernorm (per row of 1024) ----------------
__global__ __launch_bounds__(256) void ln_kernel(const unsigned short* __restrict__ in,
                                                 const float* __restrict__ gamma,
                                                 const float* __restrict__ beta,
                                                 unsigned short* __restrict__ outbf,
                                                 float* __restrict__ outf,
                                                 int final_) {
    const int r = blockIdx.x;          // 0..8159 (= s*32+b)
    const int dir = blockIdx.y;
    const int s = r >> 5, bb = r & 31;
    const size_t rowoff = ((size_t)dir * SROWS + r) * U_;
    const int tid = threadIdx.x;
    const int c = tid * 4;

    uint2 raw = *(const uint2*)(in + rowoff + c);
    float v0 = bf2f((unsigned short)(raw.x & 0xffff));
    float v1 = bf2f((unsigned short)(raw.x >> 16));
    float v2 = bf2f((unsigned short)(raw.y & 0xffff));
    float v3 = bf2f((unsigned short)(raw.y >> 16));

    float sum = v0 + v1 + v2 + v3;
    float sq = v0 * v0 + v1 * v1 + v2 * v2 + v3 * v3;
#pragma unroll
    for (int off = 32; off > 0; off >>= 1) {
        sum += __shfl_down(sum, off);
        sq  += __shfl_down(sq, off);
    }
    __shared__ float red[8];
    __shared__ float stats[2];
    const int wv = tid >> 6;
    if ((tid & 63) == 0) { red[wv] = sum; red[4 + wv] = sq; }
    __syncthreads();
    if (tid == 0) {
        float S = red[0] + red[1] + red[2] + red[3];
        float Q = red[4] + red[5] + red[6] + red[7];
        float mu = S * (1.f / 1024.f);
        float var = Q * (1.f / 1024.f) - mu * mu;
        stats[0] = mu;
        stats[1] = rsqrtf(var + 1e-3f);
    }
    __syncthreads();
    const float mu = stats[0], inv = stats[1];
    float y0 = (v0 - mu) * inv * gamma[c]     + beta[c];
    float y1 = (v1 - mu) * inv * gamma[c + 1] + beta[c + 1];
    float y2 = (v2 - mu) * inv * gamma[c + 2] + beta[c + 2];
    float y3 = (v3 - mu) * inv * gamma[c + 3] + beta[c + 3];

    if (!final_) {
        uint2 o;
        o.x = (unsigned int)f2bf(y0) | ((unsigned int)f2bf(y1) << 16);
        o.y = (unsigned int)f2bf(y2) | ((unsigned int)f2bf(y3) << 16);
        *(uint2*)(outbf + rowoff + c) = o;
    } else {
        const size_t tIdx = dir ? (size_t)(254 - s) : (size_t)s;
        const size_t o = (size_t)dir * ROWS * U_ + ((size_t)bb * TS + tIdx) * U_ + c;
        float4 y; y.x = y0; y.y = y1; y.z = y2; y.w = y3;
        *(float4*)(outf + o) = y;
    }
}

// ---------------- host ----------------
extern "C" void kernel_launch(void* const* d_in, const int* in_sizes, int n_in,
                              void* d_out, int out_size, void* d_ws, size_t ws_size,
                              hipStream_t stream) {
    (void)in_sizes; (void)n_in; (void)out_size; (void)ws_size;
    const int*   x   = (const int*)d_in[0];
    const float* emb = (const float*)d_in[1];
    const float* fW0 = (const float*)d_in[2];
    const float* fU0 = (const float*)d_in[3];
    const float* fb0 = (const float*)d_in[4];
    const float* bW0 = (const float*)d_in[5];
    const float* bU0 = (const float*)d_in[6];
    const float* bb0 = (const float*)d_in[7];
    const float* g0  = (const float*)d_in[8];
    const float* be0 = (const float*)d_in[9];
    const float* fW1 = (const float*)d_in[10];
    const float* fU1 = (const float*)d_in[11];
    const float* fb1 = (const float*)d_in[12];
    const float* bW1 = (const float*)d_in[13];
    const float* bU1 = (const float*)d_in[14];
    const float* bb1 = (const float*)d_in[15];
    const float* g1  = (const float*)d_in[16];
    const float* be1 = (const float*)d_in[17];

    // ---- aliased workspace layout (total ~219 MB) ----
    const size_t MB8  = 8388608;
    const size_t MB4  = 4194304;
    char* ws = (char*)d_ws;
    char* S0 = ws;                                           // 32 MiB, dead after scan<0>
    unsigned short* ebf  = (unsigned short*)(S0);
    unsigned short* pu0f = (unsigned short*)(S0 + MB8);
    unsigned short* pu0b = (unsigned short*)(S0 + 2 * MB8);
    unsigned short* pw0f = (unsigned short*)(S0 + 3 * MB8);
    unsigned short* pw0b = (unsigned short*)(S0 + 3 * MB8 + MB4);
    unsigned short* x1   = (unsigned short*)(S0);            // alias (after scan<0>)
    char* S1 = ws + 4 * MB8;                                 // 16 MiB
    unsigned short* pw1f = (unsigned short*)(S1);
    unsigned short* pw1b = (unsigned short*)(S1 + MB8);
    unsigned short* pu1f = (unsigned short*)(S1);            // alias (after gemm1)
    unsigned short* pu1b = (unsigned short*)(S1 + MB8);
    unsigned short* out0 = (unsigned short*)(ws + 6 * MB8);  // 32 MiB
    unsigned short* Xw   = (unsigned short*)(ws + 10 * MB8); // 128 MiB
    char* stateblob = ws + 26 * MB8;
    unsigned short* hcomm = (unsigned short*)stateblob;            // 262144 B
    float* hstate = (float*)(stateblob + 262144);
    float* cstate = (float*)(stateblob + 524288);
    unsigned int* flags = (unsigned int*)(stateblob + 786432);     // 2 layers x 64

    hipMemsetAsync(stateblob, 0, 786432 + 1024, stream);

    gather_kernel<<<dim3(B_ * T_), 256, 0, stream>>>(x, emb, ebf);

    pack_frag<<<dim3(128 * 64 / 4), 256, 0, stream>>>(fU0, pu0f, 64, 1);
    pack_frag<<<dim3(128 * 64 / 4), 256, 0, stream>>>(bU0, pu0b, 64, 1);
    pack_frag<<<dim3(128 * 32 / 4), 256, 0, stream>>>(fW0, pw0f, 32, 0);
    pack_frag<<<dim3(128 * 32 / 4), 256, 0, stream>>>(bW0, pw0b, 32, 0);
    pack_frag<<<dim3(128 * 64 / 4), 256, 0, stream>>>(fW1, pw1f, 64, 0);
    pack_frag<<<dim3(128 * 64 / 4), 256, 0, stream>>>(bW1, pw1b, 64, 0);

    // Xw0 = e @ W0 + b0  (rows = b*256+t, 8192)
    gemm_xw<32><<<dim3(64, 64, 2), 256, 0, stream>>>(ebf, 0ull, pw0f, pw0b, fb0, bb0, Xw);
    scan_kernel<0><<<dim3(64), 512, 0, stream>>>(pu0f, pu0b, Xw, x, hcomm, hstate, cstate, out0, flags);
    ln_kernel<<<dim3(ROWS, 2), 256, 0, stream>>>(out0, g0, be0, x1, nullptr, 0);
    // Xw1 = x1 @ W1 + b1  (rows = s*32+b)
    gemm_xw<64><<<dim3(64, 64, 2), 256, 0, stream>>>(x1, (unsigned long long)SROWS * U_, pw1f, pw1b, fb1, bb1, Xw);
    pack_frag<<<dim3(128 * 64 / 4), 256, 0, stream>>>(fU1, pu1f, 64, 1);
    pack_frag<<<dim3(128 * 64 / 4), 256, 0, stream>>>(bU1, pu1b, 64, 1);
    scan_kernel<1><<<dim3(64), 512, 0, stream>>>(pu1f, pu1b, Xw, x, hcomm, hstate, cstate, out0, flags + 64);
    ln_kernel<<<dim3(ROWS, 2), 256, 0, stream>>>(out0, g1, be1, nullptr, (float*)d_out, 1);
}